// Round 6
// baseline (260.833 us; speedup 1.0000x reference)
//
#include <hip/hip_runtime.h>
#include <hip/hip_bf16.h>
#include <stdint.h>

typedef __attribute__((ext_vector_type(8))) short bfrag;
typedef __attribute__((ext_vector_type(4))) short bfrag4;
typedef __attribute__((ext_vector_type(4))) float f32x4;
typedef __attribute__((ext_vector_type(2))) float f32x2;
typedef __attribute__((ext_vector_type(2))) unsigned int u32x2;

__device__ inline short f2bf(float f) {
  union { float f; uint32_t u; } v; v.f = f;
  uint32_t u = v.u;
  uint32_t r = (u + 0x7fffu + ((u >> 16) & 1u)) >> 16;
  return (short)r;
}
__device__ inline float bf2f(short s) {
  return __builtin_bit_cast(float, (uint32_t)((uint32_t)(uint16_t)s << 16));
}

#if __has_builtin(__builtin_amdgcn_cvt_pk_bf16_f32)
typedef __attribute__((ext_vector_type(2))) __bf16 bf16x2_t;
__device__ inline uint32_t pack_bf16(float a, float b) {
  bf16x2_t r = __builtin_amdgcn_cvt_pk_bf16_f32(a, b);
  return __builtin_bit_cast(uint32_t, r);
}
#else
__device__ inline uint32_t pack_bf16(float a, float b) {
  uint32_t ua = __builtin_bit_cast(uint32_t, a) + 0x8000u;
  uint32_t ub = __builtin_bit_cast(uint32_t, b) + 0x8000u;
  return __builtin_amdgcn_perm(ub, ua, 0x07060302);
}
#endif

// ---------------- prep: ada (blocks 0-15) + weight transposes (16-79) ------
__global__ __launch_bounds__(256) void prep_kernel(
    const float* __restrict__ emb_table, const int* __restrict__ t,
    const float* __restrict__ ada_w, const float* __restrict__ ada_b,
    float* __restrict__ scsh,
    const float* __restrict__ qkv_w, short* __restrict__ qkv_wt,
    const float* __restrict__ proj_w, short* __restrict__ proj_wt) {
  __shared__ float smem[64 * 65];
  const int blk = blockIdx.x;
  const int tid = threadIdx.x;
  if (blk < 16) {
    // ada: sc/sh = silu(emb_table[t]) @ ada_w + ada_b
    float* se = smem;
    float* part = smem + 256;
    int b = blk >> 3, ox = blk & 7;
    int tt = t[b];
    float e = emb_table[tt * 256 + tid];
    se[tid] = e / (1.f + __expf(-e));
    __syncthreads();
    int ol = tid & 63, kc = tid >> 6;
    int o = ox * 64 + ol;
    float acc = 0.f;
#pragma unroll 8
    for (int k = kc * 64; k < (kc + 1) * 64; ++k) acc += se[k] * ada_w[k * 512 + o];
    part[tid] = acc;
    __syncthreads();
    if (tid < 64) {
      int oo = ox * 64 + tid;
      scsh[b * 512 + oo] =
          part[tid] + part[64 + tid] + part[128 + tid] + part[192 + tid] + ada_b[oo];
    }
  } else {
    // weight transpose + fp32->bf16: Wt[n][k] = W[k][n], K=256
    const float* W; short* Wt; int N, lb;
    if (blk < 64) { W = qkv_w; Wt = qkv_wt; N = 768; lb = blk - 16; }
    else          { W = proj_w; Wt = proj_wt; N = 256; lb = blk - 64; }
    float (*tile)[65] = (float(*)[65])smem;
    int k0 = (lb & 3) * 64, n0 = (lb >> 2) * 64;
    int r = tid >> 2, c0 = (tid & 3) * 16;
    const float* src = W + (long)(k0 + r) * N + n0 + c0;
#pragma unroll
    for (int j = 0; j < 16; j += 4) {
      float4 v = *(const float4*)(src + j);
      tile[r][c0 + j] = v.x; tile[r][c0 + j + 1] = v.y;
      tile[r][c0 + j + 2] = v.z; tile[r][c0 + j + 3] = v.w;
    }
    __syncthreads();
    int nl = tid >> 2, kc = (tid & 3) * 16;
    short outv[16];
#pragma unroll
    for (int j = 0; j < 16; ++j) outv[j] = f2bf(tile[kc + j][nl]);
    short* dst = Wt + (long)(n0 + nl) * 256 + k0 + kc;
    *(bfrag*)dst = *(bfrag*)&outv[0];
    *(bfrag*)(dst + 8) = *(bfrag*)&outv[8];
  }
}

// ---------------- LayerNorm + (1+sc)*xn + sh -> bf16 ----------------------
__global__ __launch_bounds__(256) void ln_kernel(const float* __restrict__ x,
                                                 const float* __restrict__ scsh,
                                                 short* __restrict__ xb) {
  int row = blockIdx.x;            // 0..8191
  int b = row >> 12;
  int i = threadIdx.x;
  float v = x[(long)row * 256 + i];
  float s = v, sq = v * v;
#pragma unroll
  for (int off = 32; off > 0; off >>= 1) {
    s += __shfl_down(s, off);
    sq += __shfl_down(sq, off);
  }
  __shared__ float red[8];
  int w = i >> 6;
  if ((i & 63) == 0) { red[w] = s; red[4 + w] = sq; }
  __syncthreads();
  s = red[0] + red[1] + red[2] + red[3];
  sq = red[4] + red[5] + red[6] + red[7];
  float mu = s * (1.f / 256.f);
  float var = sq * (1.f / 256.f) - mu * mu;
  float xn = (v - mu) * rsqrtf(var + 1e-5f);
  float y = xn * (1.f + scsh[b * 512 + i]) + scsh[b * 512 + 256 + i];
  xb[(long)row * 256 + i] = f2bf(y);
}

// ---------------- bf16 MFMA GEMM, 128x64 tile: C = A[M,256] * Bt[N,256]^T --
// mode 0 (QKV): cols 0..511 -> qk bf16 (cols<256 scaled); 512..767 -> vT.
// mode 1 (proj): fp32, pitch N, into cout.
__global__ __launch_bounds__(256) void gemm_bf16(const short* __restrict__ A,
                                                 const short* __restrict__ Bt,
                                                 const float* __restrict__ bias,
                                                 int N, int mode, float qscale,
                                                 short* __restrict__ qk,
                                                 short* __restrict__ vT,
                                                 float* __restrict__ cout) {
  __shared__ short As[128 * 40];
  __shared__ short Bs[64 * 40];
  const int mt = blockIdx.x, nt = blockIdx.y;
  const int tid = threadIdx.x;
  const int w = tid >> 6, lane = tid & 63, l16 = lane & 15, quad = lane >> 4;
  const int ar = tid >> 1, ak = (tid & 1) * 16;   // A staging: 128 rows x 32 k
  const int br = tid >> 2, bk = (tid & 3) * 8;    // B staging: 64 rows x 32 k
  f32x4 acc[2][4] = {};
  const short* Arow = A + (long)(mt * 128 + ar) * 256 + ak;
  const short* Brow = Bt + (long)(nt * 64 + br) * 256 + bk;
  for (int kk = 0; kk < 8; ++kk) {
    __syncthreads();
    *(bfrag*)&As[ar * 40 + ak] = *(const bfrag*)(Arow + kk * 32);
    *(bfrag*)&As[ar * 40 + ak + 8] = *(const bfrag*)(Arow + kk * 32 + 8);
    *(bfrag*)&Bs[br * 40 + bk] = *(const bfrag*)(Brow + kk * 32);
    __syncthreads();
    bfrag a0 = *(const bfrag*)&As[(w * 32 + l16) * 40 + quad * 8];
    bfrag a1 = *(const bfrag*)&As[(w * 32 + 16 + l16) * 40 + quad * 8];
#pragma unroll
    for (int c = 0; c < 4; ++c) {
      bfrag bf = *(const bfrag*)&Bs[(c * 16 + l16) * 40 + quad * 8];
      acc[0][c] = __builtin_amdgcn_mfma_f32_16x16x32_bf16(a0, bf, acc[0][c], 0, 0, 0);
      acc[1][c] = __builtin_amdgcn_mfma_f32_16x16x32_bf16(a1, bf, acc[1][c], 0, 0, 0);
    }
  }
  const int rowb = mt * 128 + w * 32 + quad * 4;
  if (mode == 1) {
#pragma unroll
    for (int rg = 0; rg < 2; ++rg) {
      int row0 = rowb + rg * 16;
#pragma unroll
      for (int c = 0; c < 4; ++c) {
        int col = nt * 64 + c * 16 + l16;
        float bv = bias[col];
#pragma unroll
        for (int r = 0; r < 4; ++r)
          cout[(long)(row0 + r) * N + col] = acc[rg][c][r] + bv;
      }
    }
  } else if (nt < 8) {  // Q,K columns -> qk pitch 512
#pragma unroll
    for (int rg = 0; rg < 2; ++rg) {
      int row0 = rowb + rg * 16;
#pragma unroll
      for (int c = 0; c < 4; ++c) {
        int col = nt * 64 + c * 16 + l16;
        float bv = bias[col];
        float mult = (col < 256) ? qscale : 1.0f;
#pragma unroll
        for (int r = 0; r < 4; ++r)
          qk[(long)(row0 + r) * 512 + col] = f2bf((acc[rg][c][r] + bv) * mult);
      }
    }
  } else {  // V columns -> vT[bh][d][key], key-contiguous dwordx2 stores
    const int bb = mt >> 5;
#pragma unroll
    for (int rg = 0; rg < 2; ++rg) {
      int keyl = (rowb + rg * 16) & 4095;
#pragma unroll
      for (int c = 0; c < 4; ++c) {
        int col = nt * 64 + c * 16 + l16;
        float bv = bias[col];
        int d = col - 512;
        u32x2 dd;
        dd.x = pack_bf16(acc[rg][c][0] + bv, acc[rg][c][1] + bv);
        dd.y = pack_bf16(acc[rg][c][2] + bv, acc[rg][c][3] + bv);
        *(u32x2*)&vT[((long)(bb * 8 + (d >> 5)) * 32 + (d & 31)) * 4096 + keyl] = dd;
      }
    }
  }
}

// ---------------- flash attention (S^T scheme, 4-way key split) ------------
// Grid: qt(32) x bh(16) x ks(4). Each block: 128 q rows, keys [ks*1024, +1024).
// No max-tracking => partials combine linearly; numerators written bf16.
__global__ __launch_bounds__(256, 8) void attn_kernel(const short* __restrict__ qk,
                                                      const short* __restrict__ vT,
                                                      short* __restrict__ OpB,
                                                      float* __restrict__ lpart) {
  const int blk = blockIdx.x;
  const int qt = blk & 31;          // q tile (128 rows)
  const int bh = (blk >> 5) & 15;   // 0..15
  const int ks = blk >> 9;          // key split 0..3
  const int b = bh >> 3, hh = bh & 7;
  const int tid = threadIdx.x;
  const int w = tid >> 6, lane = tid & 63, l16 = lane & 15, quad = lane >> 4;

  __shared__ short Ks[2][64 * 40];   // K tile, row=key(64), pitch 40
  __shared__ short Vt[2][32 * 68];   // V^T tile, row=d(32), col=key(64), pitch 68

  const long rowbase = (long)b * 4096;
  const int qrow0 = qt * 128 + w * 32 + l16;
  bfrag qf0 = *(const bfrag*)&qk[(rowbase + qrow0) * 512 + hh * 32 + quad * 8];
  bfrag qf1 = *(const bfrag*)&qk[(rowbase + qrow0 + 16) * 512 + hh * 32 + quad * 8];

  f32x4 o00 = {0,0,0,0}, o10 = {0,0,0,0};  // q-group 0: d 0-15, 16-31
  f32x4 o01 = {0,0,0,0}, o11 = {0,0,0,0};  // q-group 1
  f32x2 l0 = {0.f, 0.f}, l1 = {0.f, 0.f};  // per-lane partial denominators

  const int si = tid >> 2, sk = (tid & 3) * 8;          // K: 64 rows x 32 d
  const int vrow = tid >> 3, vcol = (tid & 7) * 8;      // V^T: 32 rows x 64 keys
  const short* ksrc = qk + rowbase * 512 + 256 + hh * 32 + (long)si * 512 + sk;
  const short* vsrc = vT + ((long)bh * 32 + vrow) * 4096 + vcol;

  const int kt0 = ks * 16;
  bfrag k8 = *(const bfrag*)(ksrc + (long)kt0 * 64 * 512);
  bfrag v8 = *(const bfrag*)(vsrc + kt0 * 64);

  int buf = 0;
  for (int i = 0; i < 16; ++i) {
    *(bfrag*)&Ks[buf][si * 40 + sk] = k8;
    *(bfrag*)&Vt[buf][vrow * 68 + vcol] = v8;
    int nn = (i < 15) ? (i + 1) : 15;
    k8 = *(const bfrag*)(ksrc + (long)(kt0 + nn) * 64 * 512);
    v8 = *(const bfrag*)(vsrc + (kt0 + nn) * 64);
    __syncthreads();

    // S^T = K Q^T
    f32x4 s0[4], s1[4];
#pragma unroll
    for (int nt = 0; nt < 4; ++nt) {
      bfrag kf = *(const bfrag*)&Ks[buf][(nt * 16 + l16) * 40 + quad * 8];
      f32x4 z = {0,0,0,0};
      s0[nt] = __builtin_amdgcn_mfma_f32_16x16x32_bf16(kf, qf0, z, 0, 0, 0);
      s1[nt] = __builtin_amdgcn_mfma_f32_16x16x32_bf16(kf, qf1, z, 0, 0, 0);
    }
    // p = exp2(s); per-lane partial sums; pack to bf16 B-frags
    bfrag4 pb0[4], pb1[4];
#pragma unroll
    for (int nt = 0; nt < 4; ++nt) {
      float a0 = __builtin_amdgcn_exp2f(s0[nt][0]);
      float a1 = __builtin_amdgcn_exp2f(s0[nt][1]);
      float a2 = __builtin_amdgcn_exp2f(s0[nt][2]);
      float a3 = __builtin_amdgcn_exp2f(s0[nt][3]);
      f32x2 pa = {a0, a1}, pc = {a2, a3};
      l0 += pa; l0 += pc;
      u32x2 pk0; pk0.x = pack_bf16(a0, a1); pk0.y = pack_bf16(a2, a3);
      pb0[nt] = __builtin_bit_cast(bfrag4, pk0);
      float b0 = __builtin_amdgcn_exp2f(s1[nt][0]);
      float b1 = __builtin_amdgcn_exp2f(s1[nt][1]);
      float b2 = __builtin_amdgcn_exp2f(s1[nt][2]);
      float b3 = __builtin_amdgcn_exp2f(s1[nt][3]);
      f32x2 pb = {b0, b1}, pd = {b2, b3};
      l1 += pb; l1 += pd;
      u32x2 pk1; pk1.x = pack_bf16(b0, b1); pk1.y = pack_bf16(b2, b3);
      pb1[nt] = __builtin_bit_cast(bfrag4, pk1);
    }
    // O^T += V^T P^T
#pragma unroll
    for (int nt = 0; nt < 4; ++nt) {
      bfrag4 va = *(const bfrag4*)&Vt[buf][l16 * 68 + nt * 16 + quad * 4];
      bfrag4 vb = *(const bfrag4*)&Vt[buf][(16 + l16) * 68 + nt * 16 + quad * 4];
      o00 = __builtin_amdgcn_mfma_f32_16x16x16bf16_1k(va, pb0[nt], o00, 0, 0, 0);
      o10 = __builtin_amdgcn_mfma_f32_16x16x16bf16_1k(vb, pb0[nt], o10, 0, 0, 0);
      o01 = __builtin_amdgcn_mfma_f32_16x16x16bf16_1k(va, pb1[nt], o01, 0, 0, 0);
      o11 = __builtin_amdgcn_mfma_f32_16x16x16bf16_1k(vb, pb1[nt], o11, 0, 0, 0);
    }
    buf ^= 1;
  }
  // block-level denominators
  float ls0 = l0.x + l0.y, ls1 = l1.x + l1.y;
  ls0 += __shfl_xor(ls0, 16); ls0 += __shfl_xor(ls0, 32);
  ls1 += __shfl_xor(ls1, 16); ls1 += __shfl_xor(ls1, 32);
  // bf16 numerators + f32 denominators
  const long pb0 = (((long)ks * 16 + bh) * 4096 + qrow0) * 32;
  const long pb1 = pb0 + 16 * 32;
  u32x2 dA, dB, dC, dD;
  dA.x = pack_bf16(o00[0], o00[1]); dA.y = pack_bf16(o00[2], o00[3]);
  dB.x = pack_bf16(o10[0], o10[1]); dB.y = pack_bf16(o10[2], o10[3]);
  dC.x = pack_bf16(o01[0], o01[1]); dC.y = pack_bf16(o01[2], o01[3]);
  dD.x = pack_bf16(o11[0], o11[1]); dD.y = pack_bf16(o11[2], o11[3]);
  *(u32x2*)&OpB[pb0 + quad * 4] = dA;
  *(u32x2*)&OpB[pb0 + 16 + quad * 4] = dB;
  *(u32x2*)&OpB[pb1 + quad * 4] = dC;
  *(u32x2*)&OpB[pb1 + 16 + quad * 4] = dD;
  if (quad == 0) {
    lpart[((long)ks * 16 + bh) * 4096 + qrow0] = ls0;
    lpart[((long)ks * 16 + bh) * 4096 + qrow0 + 16] = ls1;
  }
}

// ---------------- combine key-split partials -> attn_out bf16 --------------
__global__ __launch_bounds__(256) void reduce_kernel(const short* __restrict__ OpB,
                                                     const float* __restrict__ lpart,
                                                     short* __restrict__ attn_out) {
  int row = blockIdx.x;            // 0..8191 = b*4096 + q
  int bq = row >> 12, q = row & 4095;
  int d = threadIdx.x;             // 0..255
  int h2 = d >> 5, dd = d & 31;
  int bh = bq * 8 + h2;
  float s = 0.f, l = 0.f;
#pragma unroll
  for (int ks = 0; ks < 4; ++ks) {
    long base = (long)(ks * 16 + bh) * 4096 + q;
    s += bf2f(OpB[base * 32 + dd]);
    l += lpart[base];
  }
  attn_out[(long)row * 256 + d] = f2bf(s / l);
}

extern "C" void kernel_launch(void* const* d_in, const int* in_sizes, int n_in,
                              void* d_out, int out_size, void* d_ws, size_t ws_size,
                              hipStream_t stream) {
  const float* x      = (const float*)d_in[0];
  // d_in[1] = cond (unused by reference)
  const int*   t      = (const int*)d_in[2];
  const float* emb    = (const float*)d_in[3];
  const float* ada_w  = (const float*)d_in[4];
  const float* ada_b  = (const float*)d_in[5];
  const float* qkv_w  = (const float*)d_in[6];
  const float* qkv_b  = (const float*)d_in[7];
  const float* proj_w = (const float*)d_in[8];
  const float* proj_b = (const float*)d_in[9];

  char* ws = (char*)d_ws;
  float* scsh     = (float*)(ws);                  //   4 KB  [2][512]
  short* qkv_wt   = (short*)(ws + 4096);           // 384 KB  [768][256]
  short* proj_wt  = (short*)(ws + 397312);         // 128 KB  [256][256]
  short* xb       = (short*)(ws + 528384);         //   4 MB  [8192][256]
  short* qk_out   = (short*)(ws + 4722688);        //   8 MB  [8192][512]
  short* vT       = (short*)(ws + 13111296);       //   4 MB  [16][32][4096]
  short* attn_out = (short*)(ws + 17305600);       //   4 MB  [8192][256]
  short* OpB      = (short*)(ws + 21499904);       //  16 MB  [4][16][4096][32] bf16
  float* lpart    = (float*)(ws + 38277120);       //   1 MB  [4][16][4096]

  // scale * log2(e): softmax done in exp2 domain, folded into Q columns
  const float QS = 0.17677669529663687f * 1.4426950408889634f;

  prep_kernel<<<80, 256, 0, stream>>>(emb, t, ada_w, ada_b, scsh,
                                      qkv_w, qkv_wt, proj_w, proj_wt);
  ln_kernel<<<8192, 256, 0, stream>>>(x, scsh, xb);
  gemm_bf16<<<dim3(64, 12), 256, 0, stream>>>(xb, qkv_wt, qkv_b, 768, 0, QS,
                                              qk_out, vT, nullptr);
  attn_kernel<<<2048, 256, 0, stream>>>(qk_out, vT, OpB, lpart);
  reduce_kernel<<<8192, 256, 0, stream>>>(OpB, lpart, attn_out);
  gemm_bf16<<<dim3(64, 4), 256, 0, stream>>>(attn_out, proj_wt, proj_b, 256, 1,
                                             1.0f, nullptr, nullptr, (float*)d_out);
}

// Round 7
// 172.738 us; speedup vs baseline: 1.5100x; 1.5100x over previous
//
#include <hip/hip_runtime.h>
#include <hip/hip_bf16.h>
#include <stdint.h>

typedef __attribute__((ext_vector_type(8))) short bfrag;
typedef __attribute__((ext_vector_type(4))) short bfrag4;
typedef __attribute__((ext_vector_type(4))) float f32x4;
typedef __attribute__((ext_vector_type(2))) float f32x2;
typedef __attribute__((ext_vector_type(2))) unsigned int u32x2;

__device__ inline short f2bf(float f) {
  union { float f; uint32_t u; } v; v.f = f;
  uint32_t u = v.u;
  uint32_t r = (u + 0x7fffu + ((u >> 16) & 1u)) >> 16;
  return (short)r;
}
__device__ inline float bf2f(short s) {
  return __builtin_bit_cast(float, (uint32_t)((uint32_t)(uint16_t)s << 16));
}

#if __has_builtin(__builtin_amdgcn_cvt_pk_bf16_f32)
typedef __attribute__((ext_vector_type(2))) __bf16 bf16x2_t;
__device__ inline uint32_t pack_bf16(float a, float b) {
  bf16x2_t r = __builtin_amdgcn_cvt_pk_bf16_f32(a, b);
  return __builtin_bit_cast(uint32_t, r);
}
#else
__device__ inline uint32_t pack_bf16(float a, float b) {
  uint32_t ua = __builtin_bit_cast(uint32_t, a) + 0x8000u;
  uint32_t ub = __builtin_bit_cast(uint32_t, b) + 0x8000u;
  return __builtin_amdgcn_perm(ub, ua, 0x07060302);
}
#endif

// ---------------- prep: ada (blocks 0-15) + weight transposes (16-79) ------
__global__ __launch_bounds__(256) void prep_kernel(
    const float* __restrict__ emb_table, const int* __restrict__ t,
    const float* __restrict__ ada_w, const float* __restrict__ ada_b,
    float* __restrict__ scsh,
    const float* __restrict__ qkv_w, short* __restrict__ qkv_wt,
    const float* __restrict__ proj_w, short* __restrict__ proj_wt) {
  __shared__ float smem[64 * 65];
  const int blk = blockIdx.x;
  const int tid = threadIdx.x;
  if (blk < 16) {
    // ada: sc/sh = silu(emb_table[t]) @ ada_w + ada_b
    float* se = smem;
    float* part = smem + 256;
    int b = blk >> 3, ox = blk & 7;
    int tt = t[b];
    float e = emb_table[tt * 256 + tid];
    se[tid] = e / (1.f + __expf(-e));
    __syncthreads();
    int ol = tid & 63, kc = tid >> 6;
    int o = ox * 64 + ol;
    float acc = 0.f;
#pragma unroll 8
    for (int k = kc * 64; k < (kc + 1) * 64; ++k) acc += se[k] * ada_w[k * 512 + o];
    part[tid] = acc;
    __syncthreads();
    if (tid < 64) {
      int oo = ox * 64 + tid;
      scsh[b * 512 + oo] =
          part[tid] + part[64 + tid] + part[128 + tid] + part[192 + tid] + ada_b[oo];
    }
  } else {
    // weight transpose + fp32->bf16: Wt[n][k] = W[k][n], K=256
    const float* W; short* Wt; int N, lb;
    if (blk < 64) { W = qkv_w; Wt = qkv_wt; N = 768; lb = blk - 16; }
    else          { W = proj_w; Wt = proj_wt; N = 256; lb = blk - 64; }
    float (*tile)[65] = (float(*)[65])smem;
    int k0 = (lb & 3) * 64, n0 = (lb >> 2) * 64;
    int r = tid >> 2, c0 = (tid & 3) * 16;
    const float* src = W + (long)(k0 + r) * N + n0 + c0;
#pragma unroll
    for (int j = 0; j < 16; j += 4) {
      float4 v = *(const float4*)(src + j);
      tile[r][c0 + j] = v.x; tile[r][c0 + j + 1] = v.y;
      tile[r][c0 + j + 2] = v.z; tile[r][c0 + j + 3] = v.w;
    }
    __syncthreads();
    int nl = tid >> 2, kc = (tid & 3) * 16;
    short outv[16];
#pragma unroll
    for (int j = 0; j < 16; ++j) outv[j] = f2bf(tile[kc + j][nl]);
    short* dst = Wt + (long)(n0 + nl) * 256 + k0 + kc;
    *(bfrag*)dst = *(bfrag*)&outv[0];
    *(bfrag*)(dst + 8) = *(bfrag*)&outv[8];
  }
}

// ---------------- LayerNorm + (1+sc)*xn + sh -> bf16 ----------------------
__global__ __launch_bounds__(256) void ln_kernel(const float* __restrict__ x,
                                                 const float* __restrict__ scsh,
                                                 short* __restrict__ xb) {
  int row = blockIdx.x;            // 0..8191
  int b = row >> 12;
  int i = threadIdx.x;
  float v = x[(long)row * 256 + i];
  float s = v, sq = v * v;
#pragma unroll
  for (int off = 32; off > 0; off >>= 1) {
    s += __shfl_down(s, off);
    sq += __shfl_down(sq, off);
  }
  __shared__ float red[8];
  int w = i >> 6;
  if ((i & 63) == 0) { red[w] = s; red[4 + w] = sq; }
  __syncthreads();
  s = red[0] + red[1] + red[2] + red[3];
  sq = red[4] + red[5] + red[6] + red[7];
  float mu = s * (1.f / 256.f);
  float var = sq * (1.f / 256.f) - mu * mu;
  float xn = (v - mu) * rsqrtf(var + 1e-5f);
  float y = xn * (1.f + scsh[b * 512 + i]) + scsh[b * 512 + 256 + i];
  xb[(long)row * 256 + i] = f2bf(y);
}

// ---------------- bf16 MFMA GEMM, 128x64 tile: C = A[M,256] * Bt[N,256]^T --
// mode 0 (QKV): cols 0..511 -> qk bf16 (cols<256 scaled); 512..767 -> vT.
// mode 1 (proj): fp32, pitch N, into cout.
__global__ __launch_bounds__(256) void gemm_bf16(const short* __restrict__ A,
                                                 const short* __restrict__ Bt,
                                                 const float* __restrict__ bias,
                                                 int N, int mode, float qscale,
                                                 short* __restrict__ qk,
                                                 short* __restrict__ vT,
                                                 float* __restrict__ cout) {
  __shared__ short As[128 * 40];
  __shared__ short Bs[64 * 40];
  const int mt = blockIdx.x, nt = blockIdx.y;
  const int tid = threadIdx.x;
  const int w = tid >> 6, lane = tid & 63, l16 = lane & 15, quad = lane >> 4;
  const int ar = tid >> 1, ak = (tid & 1) * 16;   // A staging: 128 rows x 32 k
  const int br = tid >> 2, bk = (tid & 3) * 8;    // B staging: 64 rows x 32 k
  f32x4 acc[2][4] = {};
  const short* Arow = A + (long)(mt * 128 + ar) * 256 + ak;
  const short* Brow = Bt + (long)(nt * 64 + br) * 256 + bk;
  for (int kk = 0; kk < 8; ++kk) {
    __syncthreads();
    *(bfrag*)&As[ar * 40 + ak] = *(const bfrag*)(Arow + kk * 32);
    *(bfrag*)&As[ar * 40 + ak + 8] = *(const bfrag*)(Arow + kk * 32 + 8);
    *(bfrag*)&Bs[br * 40 + bk] = *(const bfrag*)(Brow + kk * 32);
    __syncthreads();
    bfrag a0 = *(const bfrag*)&As[(w * 32 + l16) * 40 + quad * 8];
    bfrag a1 = *(const bfrag*)&As[(w * 32 + 16 + l16) * 40 + quad * 8];
#pragma unroll
    for (int c = 0; c < 4; ++c) {
      bfrag bf = *(const bfrag*)&Bs[(c * 16 + l16) * 40 + quad * 8];
      acc[0][c] = __builtin_amdgcn_mfma_f32_16x16x32_bf16(a0, bf, acc[0][c], 0, 0, 0);
      acc[1][c] = __builtin_amdgcn_mfma_f32_16x16x32_bf16(a1, bf, acc[1][c], 0, 0, 0);
    }
  }
  const int rowb = mt * 128 + w * 32 + quad * 4;
  if (mode == 1) {
#pragma unroll
    for (int rg = 0; rg < 2; ++rg) {
      int row0 = rowb + rg * 16;
#pragma unroll
      for (int c = 0; c < 4; ++c) {
        int col = nt * 64 + c * 16 + l16;
        float bv = bias[col];
#pragma unroll
        for (int r = 0; r < 4; ++r)
          cout[(long)(row0 + r) * N + col] = acc[rg][c][r] + bv;
      }
    }
  } else if (nt < 8) {  // Q,K columns -> qk pitch 512
#pragma unroll
    for (int rg = 0; rg < 2; ++rg) {
      int row0 = rowb + rg * 16;
#pragma unroll
      for (int c = 0; c < 4; ++c) {
        int col = nt * 64 + c * 16 + l16;
        float bv = bias[col];
        float mult = (col < 256) ? qscale : 1.0f;
#pragma unroll
        for (int r = 0; r < 4; ++r)
          qk[(long)(row0 + r) * 512 + col] = f2bf((acc[rg][c][r] + bv) * mult);
      }
    }
  } else {  // V columns -> vT[bh][d][key], key-contiguous dwordx2 stores
    const int bb = mt >> 5;
#pragma unroll
    for (int rg = 0; rg < 2; ++rg) {
      int keyl = (rowb + rg * 16) & 4095;
#pragma unroll
      for (int c = 0; c < 4; ++c) {
        int col = nt * 64 + c * 16 + l16;
        float bv = bias[col];
        int d = col - 512;
        u32x2 dd;
        dd.x = pack_bf16(acc[rg][c][0] + bv, acc[rg][c][1] + bv);
        dd.y = pack_bf16(acc[rg][c][2] + bv, acc[rg][c][3] + bv);
        *(u32x2*)&vT[((long)(bb * 8 + (d >> 5)) * 32 + (d & 31)) * 4096 + keyl] = dd;
      }
    }
  }
}

// ---------------- flash attention (S^T scheme, 4-way key split) ------------
// Grid: qt(32) x bh(16) x ks(4). Each block: 128 q rows, keys [ks*1024, +1024).
// No max-tracking => partials combine linearly; numerators written bf16.
// NOTE: no min-waves clamp — VGPR 56 naturally allows 8 waves/SIMD; a forced
// __launch_bounds__(256,8) squeezed VGPR to 32 and spilled ~520 MB to scratch.
__global__ __launch_bounds__(256) void attn_kernel(const short* __restrict__ qk,
                                                   const short* __restrict__ vT,
                                                   short* __restrict__ OpB,
                                                   float* __restrict__ lpart) {
  const int blk = blockIdx.x;
  const int qt = blk & 31;          // q tile (128 rows)
  const int bh = (blk >> 5) & 15;   // 0..15
  const int ks = blk >> 9;          // key split 0..3
  const int b = bh >> 3, hh = bh & 7;
  const int tid = threadIdx.x;
  const int w = tid >> 6, lane = tid & 63, l16 = lane & 15, quad = lane >> 4;

  __shared__ short Ks[2][64 * 40];   // K tile, row=key(64), pitch 40
  __shared__ short Vt[2][32 * 68];   // V^T tile, row=d(32), col=key(64), pitch 68

  const long rowbase = (long)b * 4096;
  const int qrow0 = qt * 128 + w * 32 + l16;
  bfrag qf0 = *(const bfrag*)&qk[(rowbase + qrow0) * 512 + hh * 32 + quad * 8];
  bfrag qf1 = *(const bfrag*)&qk[(rowbase + qrow0 + 16) * 512 + hh * 32 + quad * 8];

  f32x4 o00 = {0,0,0,0}, o10 = {0,0,0,0};  // q-group 0: d 0-15, 16-31
  f32x4 o01 = {0,0,0,0}, o11 = {0,0,0,0};  // q-group 1
  f32x2 l0 = {0.f, 0.f}, l1 = {0.f, 0.f};  // per-lane partial denominators

  const int si = tid >> 2, sk = (tid & 3) * 8;          // K: 64 rows x 32 d
  const int vrow = tid >> 3, vcol = (tid & 7) * 8;      // V^T: 32 rows x 64 keys
  const short* ksrc = qk + rowbase * 512 + 256 + hh * 32 + (long)si * 512 + sk;
  const short* vsrc = vT + ((long)bh * 32 + vrow) * 4096 + vcol;

  const int kt0 = ks * 16;
  bfrag k8 = *(const bfrag*)(ksrc + (long)kt0 * 64 * 512);
  bfrag v8 = *(const bfrag*)(vsrc + kt0 * 64);

  int buf = 0;
  for (int i = 0; i < 16; ++i) {
    *(bfrag*)&Ks[buf][si * 40 + sk] = k8;
    *(bfrag*)&Vt[buf][vrow * 68 + vcol] = v8;
    int nn = (i < 15) ? (i + 1) : 15;
    k8 = *(const bfrag*)(ksrc + (long)(kt0 + nn) * 64 * 512);
    v8 = *(const bfrag*)(vsrc + (kt0 + nn) * 64);
    __syncthreads();

    // S^T = K Q^T
    f32x4 s0[4], s1[4];
#pragma unroll
    for (int nt = 0; nt < 4; ++nt) {
      bfrag kf = *(const bfrag*)&Ks[buf][(nt * 16 + l16) * 40 + quad * 8];
      f32x4 z = {0,0,0,0};
      s0[nt] = __builtin_amdgcn_mfma_f32_16x16x32_bf16(kf, qf0, z, 0, 0, 0);
      s1[nt] = __builtin_amdgcn_mfma_f32_16x16x32_bf16(kf, qf1, z, 0, 0, 0);
    }
    // p = exp2(s); per-lane partial sums; pack to bf16 B-frags
    bfrag4 pb0[4], pb1[4];
#pragma unroll
    for (int nt = 0; nt < 4; ++nt) {
      float a0 = __builtin_amdgcn_exp2f(s0[nt][0]);
      float a1 = __builtin_amdgcn_exp2f(s0[nt][1]);
      float a2 = __builtin_amdgcn_exp2f(s0[nt][2]);
      float a3 = __builtin_amdgcn_exp2f(s0[nt][3]);
      f32x2 pa = {a0, a1}, pc = {a2, a3};
      l0 += pa; l0 += pc;
      u32x2 pk0; pk0.x = pack_bf16(a0, a1); pk0.y = pack_bf16(a2, a3);
      pb0[nt] = __builtin_bit_cast(bfrag4, pk0);
      float b0 = __builtin_amdgcn_exp2f(s1[nt][0]);
      float b1 = __builtin_amdgcn_exp2f(s1[nt][1]);
      float b2 = __builtin_amdgcn_exp2f(s1[nt][2]);
      float b3 = __builtin_amdgcn_exp2f(s1[nt][3]);
      f32x2 pb = {b0, b1}, pd = {b2, b3};
      l1 += pb; l1 += pd;
      u32x2 pk1; pk1.x = pack_bf16(b0, b1); pk1.y = pack_bf16(b2, b3);
      pb1[nt] = __builtin_bit_cast(bfrag4, pk1);
    }
    // O^T += V^T P^T
#pragma unroll
    for (int nt = 0; nt < 4; ++nt) {
      bfrag4 va = *(const bfrag4*)&Vt[buf][l16 * 68 + nt * 16 + quad * 4];
      bfrag4 vb = *(const bfrag4*)&Vt[buf][(16 + l16) * 68 + nt * 16 + quad * 4];
      o00 = __builtin_amdgcn_mfma_f32_16x16x16bf16_1k(va, pb0[nt], o00, 0, 0, 0);
      o10 = __builtin_amdgcn_mfma_f32_16x16x16bf16_1k(vb, pb0[nt], o10, 0, 0, 0);
      o01 = __builtin_amdgcn_mfma_f32_16x16x16bf16_1k(va, pb1[nt], o01, 0, 0, 0);
      o11 = __builtin_amdgcn_mfma_f32_16x16x16bf16_1k(vb, pb1[nt], o11, 0, 0, 0);
    }
    buf ^= 1;
  }
  // block-level denominators
  float ls0 = l0.x + l0.y, ls1 = l1.x + l1.y;
  ls0 += __shfl_xor(ls0, 16); ls0 += __shfl_xor(ls0, 32);
  ls1 += __shfl_xor(ls1, 16); ls1 += __shfl_xor(ls1, 32);
  // bf16 numerators + f32 denominators
  const long pb0 = (((long)ks * 16 + bh) * 4096 + qrow0) * 32;
  const long pb1 = pb0 + 16 * 32;
  u32x2 dA, dB, dC, dD;
  dA.x = pack_bf16(o00[0], o00[1]); dA.y = pack_bf16(o00[2], o00[3]);
  dB.x = pack_bf16(o10[0], o10[1]); dB.y = pack_bf16(o10[2], o10[3]);
  dC.x = pack_bf16(o01[0], o01[1]); dC.y = pack_bf16(o01[2], o01[3]);
  dD.x = pack_bf16(o11[0], o11[1]); dD.y = pack_bf16(o11[2], o11[3]);
  *(u32x2*)&OpB[pb0 + quad * 4] = dA;
  *(u32x2*)&OpB[pb0 + 16 + quad * 4] = dB;
  *(u32x2*)&OpB[pb1 + quad * 4] = dC;
  *(u32x2*)&OpB[pb1 + 16 + quad * 4] = dD;
  if (quad == 0) {
    lpart[((long)ks * 16 + bh) * 4096 + qrow0] = ls0;
    lpart[((long)ks * 16 + bh) * 4096 + qrow0 + 16] = ls1;
  }
}

// ---------------- combine key-split partials -> attn_out bf16 --------------
__global__ __launch_bounds__(256) void reduce_kernel(const short* __restrict__ OpB,
                                                     const float* __restrict__ lpart,
                                                     short* __restrict__ attn_out) {
  int row = blockIdx.x;            // 0..8191 = b*4096 + q
  int bq = row >> 12, q = row & 4095;
  int d = threadIdx.x;             // 0..255
  int h2 = d >> 5, dd = d & 31;
  int bh = bq * 8 + h2;
  float s = 0.f, l = 0.f;
#pragma unroll
  for (int ks = 0; ks < 4; ++ks) {
    long base = (long)(ks * 16 + bh) * 4096 + q;
    s += bf2f(OpB[base * 32 + dd]);
    l += lpart[base];
  }
  attn_out[(long)row * 256 + d] = f2bf(s / l);
}

extern "C" void kernel_launch(void* const* d_in, const int* in_sizes, int n_in,
                              void* d_out, int out_size, void* d_ws, size_t ws_size,
                              hipStream_t stream) {
  const float* x      = (const float*)d_in[0];
  // d_in[1] = cond (unused by reference)
  const int*   t      = (const int*)d_in[2];
  const float* emb    = (const float*)d_in[3];
  const float* ada_w  = (const float*)d_in[4];
  const float* ada_b  = (const float*)d_in[5];
  const float* qkv_w  = (const float*)d_in[6];
  const float* qkv_b  = (const float*)d_in[7];
  const float* proj_w = (const float*)d_in[8];
  const float* proj_b = (const float*)d_in[9];

  char* ws = (char*)d_ws;
  float* scsh     = (float*)(ws);                  //   4 KB  [2][512]
  short* qkv_wt   = (short*)(ws + 4096);           // 384 KB  [768][256]
  short* proj_wt  = (short*)(ws + 397312);         // 128 KB  [256][256]
  short* xb       = (short*)(ws + 528384);         //   4 MB  [8192][256]
  short* qk_out   = (short*)(ws + 4722688);        //   8 MB  [8192][512]
  short* vT       = (short*)(ws + 13111296);       //   4 MB  [16][32][4096]
  short* attn_out = (short*)(ws + 17305600);       //   4 MB  [8192][256]
  short* OpB      = (short*)(ws + 21499904);       //  16 MB  [4][16][4096][32] bf16
  float* lpart    = (float*)(ws + 38277120);       //   1 MB  [4][16][4096]

  // scale * log2(e): softmax done in exp2 domain, folded into Q columns
  const float QS = 0.17677669529663687f * 1.4426950408889634f;

  prep_kernel<<<80, 256, 0, stream>>>(emb, t, ada_w, ada_b, scsh,
                                      qkv_w, qkv_wt, proj_w, proj_wt);
  ln_kernel<<<8192, 256, 0, stream>>>(x, scsh, xb);
  gemm_bf16<<<dim3(64, 12), 256, 0, stream>>>(xb, qkv_wt, qkv_b, 768, 0, QS,
                                              qk_out, vT, nullptr);
  attn_kernel<<<2048, 256, 0, stream>>>(qk_out, vT, OpB, lpart);
  reduce_kernel<<<8192, 256, 0, stream>>>(OpB, lpart, attn_out);
  gemm_bf16<<<dim3(64, 4), 256, 0, stream>>>(attn_out, proj_wt, proj_b, 256, 1,
                                             1.0f, nullptr, nullptr, (float*)d_out);
}

// Round 8
// 169.676 us; speedup vs baseline: 1.5372x; 1.0180x over previous
//
#include <hip/hip_runtime.h>
#include <hip/hip_bf16.h>
#include <stdint.h>

typedef __attribute__((ext_vector_type(8))) short bfrag;
typedef __attribute__((ext_vector_type(4))) short bfrag4;
typedef __attribute__((ext_vector_type(4))) float f32x4;
typedef __attribute__((ext_vector_type(2))) float f32x2;
typedef __attribute__((ext_vector_type(2))) unsigned int u32x2;

__device__ inline short f2bf(float f) {
  union { float f; uint32_t u; } v; v.f = f;
  uint32_t u = v.u;
  uint32_t r = (u + 0x7fffu + ((u >> 16) & 1u)) >> 16;
  return (short)r;
}
__device__ inline float bf2f(short s) {
  return __builtin_bit_cast(float, (uint32_t)((uint32_t)(uint16_t)s << 16));
}

#if __has_builtin(__builtin_amdgcn_cvt_pk_bf16_f32)
typedef __attribute__((ext_vector_type(2))) __bf16 bf16x2_t;
__device__ inline uint32_t pack_bf16(float a, float b) {
  bf16x2_t r = __builtin_amdgcn_cvt_pk_bf16_f32(a, b);
  return __builtin_bit_cast(uint32_t, r);
}
#else
__device__ inline uint32_t pack_bf16(float a, float b) {
  uint32_t ua = __builtin_bit_cast(uint32_t, a) + 0x8000u;
  uint32_t ub = __builtin_bit_cast(uint32_t, b) + 0x8000u;
  return __builtin_amdgcn_perm(ub, ua, 0x07060302);
}
#endif

// ---------------- prep: ada (blocks 0-15) + weight transposes (16-79) ------
__global__ __launch_bounds__(256) void prep_kernel(
    const float* __restrict__ emb_table, const int* __restrict__ t,
    const float* __restrict__ ada_w, const float* __restrict__ ada_b,
    float* __restrict__ scsh,
    const float* __restrict__ qkv_w, short* __restrict__ qkv_wt,
    const float* __restrict__ proj_w, short* __restrict__ proj_wt) {
  __shared__ float smem[64 * 65];
  const int blk = blockIdx.x;
  const int tid = threadIdx.x;
  if (blk < 16) {
    float* se = smem;
    float* part = smem + 256;
    int b = blk >> 3, ox = blk & 7;
    int tt = t[b];
    float e = emb_table[tt * 256 + tid];
    se[tid] = e / (1.f + __expf(-e));
    __syncthreads();
    int ol = tid & 63, kc = tid >> 6;
    int o = ox * 64 + ol;
    float acc = 0.f;
#pragma unroll 8
    for (int k = kc * 64; k < (kc + 1) * 64; ++k) acc += se[k] * ada_w[k * 512 + o];
    part[tid] = acc;
    __syncthreads();
    if (tid < 64) {
      int oo = ox * 64 + tid;
      scsh[b * 512 + oo] =
          part[tid] + part[64 + tid] + part[128 + tid] + part[192 + tid] + ada_b[oo];
    }
  } else {
    const float* W; short* Wt; int N, lb;
    if (blk < 64) { W = qkv_w; Wt = qkv_wt; N = 768; lb = blk - 16; }
    else          { W = proj_w; Wt = proj_wt; N = 256; lb = blk - 64; }
    float (*tile)[65] = (float(*)[65])smem;
    int k0 = (lb & 3) * 64, n0 = (lb >> 2) * 64;
    int r = tid >> 2, c0 = (tid & 3) * 16;
    const float* src = W + (long)(k0 + r) * N + n0 + c0;
#pragma unroll
    for (int j = 0; j < 16; j += 4) {
      float4 v = *(const float4*)(src + j);
      tile[r][c0 + j] = v.x; tile[r][c0 + j + 1] = v.y;
      tile[r][c0 + j + 2] = v.z; tile[r][c0 + j + 3] = v.w;
    }
    __syncthreads();
    int nl = tid >> 2, kc = (tid & 3) * 16;
    short outv[16];
#pragma unroll
    for (int j = 0; j < 16; ++j) outv[j] = f2bf(tile[kc + j][nl]);
    short* dst = Wt + (long)(n0 + nl) * 256 + k0 + kc;
    *(bfrag*)dst = *(bfrag*)&outv[0];
    *(bfrag*)(dst + 8) = *(bfrag*)&outv[8];
  }
}

// ---------------- LayerNorm + (1+sc)*xn + sh -> bf16, wave-per-row ---------
__global__ __launch_bounds__(256) void ln_kernel(const float* __restrict__ x,
                                                 const float* __restrict__ scsh,
                                                 short* __restrict__ xb) {
  int row = blockIdx.x * 4 + (threadIdx.x >> 6);   // 2048 blocks x 4 rows
  int b = row >> 12;
  int lane = threadIdx.x & 63;
  float4 v = *(const float4*)(x + (long)row * 256 + lane * 4);
  float s = v.x + v.y + v.z + v.w;
  float sq = v.x * v.x + v.y * v.y + v.z * v.z + v.w * v.w;
#pragma unroll
  for (int off = 32; off > 0; off >>= 1) {
    s += __shfl_xor(s, off);
    sq += __shfl_xor(sq, off);
  }
  float mu = s * (1.f / 256.f);
  float var = sq * (1.f / 256.f) - mu * mu;
  float rstd = rsqrtf(var + 1e-5f);
  const float* scp = scsh + b * 512 + lane * 4;
  float4 sc = *(const float4*)scp;
  float4 sh = *(const float4*)(scp + 256);
  float y0 = (v.x - mu) * rstd * (1.f + sc.x) + sh.x;
  float y1 = (v.y - mu) * rstd * (1.f + sc.y) + sh.y;
  float y2 = (v.z - mu) * rstd * (1.f + sc.z) + sh.z;
  float y3 = (v.w - mu) * rstd * (1.f + sc.w) + sh.w;
  u32x2 o; o.x = pack_bf16(y0, y1); o.y = pack_bf16(y2, y3);
  *(u32x2*)&xb[(long)row * 256 + lane * 4] = o;
}

// ---------------- bf16 MFMA GEMM, 128x64 tile: C = A[M,256] * Bt[N,256]^T --
// Register-prefetch AFTER the 2nd barrier so global loads overlap MFMA.
// mode 0 (QKV): cols 0..511 -> qk bf16 (cols<256 scaled); 512..767 -> vT.
// mode 1 (proj): fp32, pitch N, into cout.
__global__ __launch_bounds__(256) void gemm_bf16(const short* __restrict__ A,
                                                 const short* __restrict__ Bt,
                                                 const float* __restrict__ bias,
                                                 int N, int mode, float qscale,
                                                 short* __restrict__ qk,
                                                 short* __restrict__ vT,
                                                 float* __restrict__ cout) {
  __shared__ short As[128 * 40];
  __shared__ short Bs[64 * 40];
  const int mt = blockIdx.x, nt = blockIdx.y;
  const int tid = threadIdx.x;
  const int w = tid >> 6, lane = tid & 63, l16 = lane & 15, quad = lane >> 4;
  const int ar = tid >> 1, ak = (tid & 1) * 16;   // A staging: 128 rows x 32 k
  const int br = tid >> 2, bk = (tid & 3) * 8;    // B staging: 64 rows x 32 k
  f32x4 acc[2][4] = {};
  const short* Arow = A + (long)(mt * 128 + ar) * 256 + ak;
  const short* Brow = Bt + (long)(nt * 64 + br) * 256 + bk;
  bfrag a8a = *(const bfrag*)Arow;
  bfrag a8b = *(const bfrag*)(Arow + 8);
  bfrag b8  = *(const bfrag*)Brow;
  for (int kk = 0; kk < 8; ++kk) {
    __syncthreads();
    *(bfrag*)&As[ar * 40 + ak] = a8a;
    *(bfrag*)&As[ar * 40 + ak + 8] = a8b;
    *(bfrag*)&Bs[br * 40 + bk] = b8;
    __syncthreads();
    int kn = (kk < 7) ? (kk + 1) : 7;
    a8a = *(const bfrag*)(Arow + kn * 32);
    a8b = *(const bfrag*)(Arow + kn * 32 + 8);
    b8  = *(const bfrag*)(Brow + kn * 32);
    bfrag a0 = *(const bfrag*)&As[(w * 32 + l16) * 40 + quad * 8];
    bfrag a1 = *(const bfrag*)&As[(w * 32 + 16 + l16) * 40 + quad * 8];
#pragma unroll
    for (int c = 0; c < 4; ++c) {
      bfrag bf = *(const bfrag*)&Bs[(c * 16 + l16) * 40 + quad * 8];
      acc[0][c] = __builtin_amdgcn_mfma_f32_16x16x32_bf16(a0, bf, acc[0][c], 0, 0, 0);
      acc[1][c] = __builtin_amdgcn_mfma_f32_16x16x32_bf16(a1, bf, acc[1][c], 0, 0, 0);
    }
  }
  const int rowb = mt * 128 + w * 32 + quad * 4;
  if (mode == 1) {
#pragma unroll
    for (int rg = 0; rg < 2; ++rg) {
      int row0 = rowb + rg * 16;
#pragma unroll
      for (int c = 0; c < 4; ++c) {
        int col = nt * 64 + c * 16 + l16;
        float bv = bias[col];
#pragma unroll
        for (int r = 0; r < 4; ++r)
          cout[(long)(row0 + r) * N + col] = acc[rg][c][r] + bv;
      }
    }
  } else if (nt < 8) {  // Q,K columns -> qk pitch 512
#pragma unroll
    for (int rg = 0; rg < 2; ++rg) {
      int row0 = rowb + rg * 16;
#pragma unroll
      for (int c = 0; c < 4; ++c) {
        int col = nt * 64 + c * 16 + l16;
        float bv = bias[col];
        float mult = (col < 256) ? qscale : 1.0f;
#pragma unroll
        for (int r = 0; r < 4; ++r)
          qk[(long)(row0 + r) * 512 + col] = f2bf((acc[rg][c][r] + bv) * mult);
      }
    }
  } else {  // V columns -> vT[bh][d][key], key-contiguous dwordx2 stores
    const int bb = mt >> 5;
#pragma unroll
    for (int rg = 0; rg < 2; ++rg) {
      int keyl = (rowb + rg * 16) & 4095;
#pragma unroll
      for (int c = 0; c < 4; ++c) {
        int col = nt * 64 + c * 16 + l16;
        float bv = bias[col];
        int d = col - 512;
        u32x2 dd;
        dd.x = pack_bf16(acc[rg][c][0] + bv, acc[rg][c][1] + bv);
        dd.y = pack_bf16(acc[rg][c][2] + bv, acc[rg][c][3] + bv);
        *(u32x2*)&vT[((long)(bb * 8 + (d >> 5)) * 32 + (d & 31)) * 4096 + keyl] = dd;
      }
    }
  }
}

// ---------------- flash attention (S^T scheme, 4 q-groups/wave, ks=4) ------
// Grid: qt(16) x bh(16) x ks(4). Block: 256 q rows, keys [ks*1024, +1024).
// Each wave: 64 q rows; every kf/va LDS read feeds 4 q-group MFMA chains.
// Prefetch issued AFTER the barrier so loads overlap the compute phase.
__global__ __launch_bounds__(256) void attn_kernel(const short* __restrict__ qk,
                                                   const short* __restrict__ vT,
                                                   short* __restrict__ OpB,
                                                   float* __restrict__ lpart) {
  const int blk = blockIdx.x;
  const int qt = blk & 15;          // q tile (256 rows)
  const int bh = (blk >> 4) & 15;   // 0..15
  const int ks = blk >> 8;          // key split 0..3
  const int b = bh >> 3, hh = bh & 7;
  const int tid = threadIdx.x;
  const int w = tid >> 6, lane = tid & 63, l16 = lane & 15, quad = lane >> 4;

  __shared__ short Ks[2][64 * 40];   // K tile, row=key(64), pitch 40
  __shared__ short Vt[2][32 * 68];   // V^T tile, row=d(32), col=key(64), pitch 68

  const long rowbase = (long)b * 4096;
  const int qrow0 = qt * 256 + w * 64 + l16;
  bfrag qf[4];
#pragma unroll
  for (int g = 0; g < 4; ++g)
    qf[g] = *(const bfrag*)&qk[(rowbase + qrow0 + g * 16) * 512 + hh * 32 + quad * 8];

  f32x4 o0[4] = {}, o1[4] = {};      // per q-group: d 0-15 / d 16-31
  f32x2 lsum[4] = {};                // per-lane partial denominators

  const int si = tid >> 2, sk = (tid & 3) * 8;          // K: 64 rows x 32 d
  const int vrow = tid >> 3, vcol = (tid & 7) * 8;      // V^T: 32 rows x 64 keys
  const short* ksrc = qk + rowbase * 512 + 256 + hh * 32 + (long)si * 512 + sk;
  const short* vsrc = vT + ((long)bh * 32 + vrow) * 4096 + vcol;

  const int kt0 = ks * 16;
  bfrag k8 = *(const bfrag*)(ksrc + (long)kt0 * 64 * 512);
  bfrag v8 = *(const bfrag*)(vsrc + kt0 * 64);

  int buf = 0;
  for (int i = 0; i < 16; ++i) {
    *(bfrag*)&Ks[buf][si * 40 + sk] = k8;
    *(bfrag*)&Vt[buf][vrow * 68 + vcol] = v8;
    __syncthreads();
    // prefetch AFTER the barrier: overlaps with the compute below
    int nn = (i < 15) ? (i + 1) : 15;
    k8 = *(const bfrag*)(ksrc + (long)(kt0 + nn) * 64 * 512);
    v8 = *(const bfrag*)(vsrc + (kt0 + nn) * 64);

#pragma unroll
    for (int nt = 0; nt < 4; ++nt) {
      bfrag kf = *(const bfrag*)&Ks[buf][(nt * 16 + l16) * 40 + quad * 8];
      f32x4 z = {0,0,0,0};
      f32x4 s[4];
      s[0] = __builtin_amdgcn_mfma_f32_16x16x32_bf16(kf, qf[0], z, 0, 0, 0);
      s[1] = __builtin_amdgcn_mfma_f32_16x16x32_bf16(kf, qf[1], z, 0, 0, 0);
      s[2] = __builtin_amdgcn_mfma_f32_16x16x32_bf16(kf, qf[2], z, 0, 0, 0);
      s[3] = __builtin_amdgcn_mfma_f32_16x16x32_bf16(kf, qf[3], z, 0, 0, 0);
      bfrag4 pb[4];
#pragma unroll
      for (int g = 0; g < 4; ++g) {
        float p0 = __builtin_amdgcn_exp2f(s[g][0]);
        float p1 = __builtin_amdgcn_exp2f(s[g][1]);
        float p2 = __builtin_amdgcn_exp2f(s[g][2]);
        float p3 = __builtin_amdgcn_exp2f(s[g][3]);
        f32x2 pa = {p0, p1}, pc = {p2, p3};
        lsum[g] += pa; lsum[g] += pc;
        u32x2 pk; pk.x = pack_bf16(p0, p1); pk.y = pack_bf16(p2, p3);
        pb[g] = __builtin_bit_cast(bfrag4, pk);
      }
      bfrag4 va = *(const bfrag4*)&Vt[buf][l16 * 68 + nt * 16 + quad * 4];
      bfrag4 vb = *(const bfrag4*)&Vt[buf][(16 + l16) * 68 + nt * 16 + quad * 4];
#pragma unroll
      for (int g = 0; g < 4; ++g) {
        o0[g] = __builtin_amdgcn_mfma_f32_16x16x16bf16_1k(va, pb[g], o0[g], 0, 0, 0);
        o1[g] = __builtin_amdgcn_mfma_f32_16x16x16bf16_1k(vb, pb[g], o1[g], 0, 0, 0);
      }
    }
    buf ^= 1;
  }
  // epilogue: per q-group denominators + bf16 numerators
#pragma unroll
  for (int g = 0; g < 4; ++g) {
    float ls = lsum[g].x + lsum[g].y;
    ls += __shfl_xor(ls, 16); ls += __shfl_xor(ls, 32);
    const long pbase = (((long)ks * 16 + bh) * 4096 + qrow0 + g * 16) * 32;
    u32x2 dA, dB;
    dA.x = pack_bf16(o0[g][0], o0[g][1]); dA.y = pack_bf16(o0[g][2], o0[g][3]);
    dB.x = pack_bf16(o1[g][0], o1[g][1]); dB.y = pack_bf16(o1[g][2], o1[g][3]);
    *(u32x2*)&OpB[pbase + quad * 4] = dA;
    *(u32x2*)&OpB[pbase + 16 + quad * 4] = dB;
    if (quad == 0)
      lpart[((long)ks * 16 + bh) * 4096 + qrow0 + g * 16] = ls;
  }
}

// ---------------- combine key-split partials -> attn_out bf16 --------------
__global__ __launch_bounds__(256) void reduce_kernel(const short* __restrict__ OpB,
                                                     const float* __restrict__ lpart,
                                                     short* __restrict__ attn_out) {
  int row = blockIdx.x;            // 0..8191 = b*4096 + q
  int bq = row >> 12, q = row & 4095;
  int d = threadIdx.x;             // 0..255
  int h2 = d >> 5, dd = d & 31;
  int bh = bq * 8 + h2;
  float s = 0.f, l = 0.f;
#pragma unroll
  for (int ks = 0; ks < 4; ++ks) {
    long base = (long)(ks * 16 + bh) * 4096 + q;
    s += bf2f(OpB[base * 32 + dd]);
    l += lpart[base];
  }
  attn_out[(long)row * 256 + d] = f2bf(s / l);
}

extern "C" void kernel_launch(void* const* d_in, const int* in_sizes, int n_in,
                              void* d_out, int out_size, void* d_ws, size_t ws_size,
                              hipStream_t stream) {
  const float* x      = (const float*)d_in[0];
  // d_in[1] = cond (unused by reference)
  const int*   t      = (const int*)d_in[2];
  const float* emb    = (const float*)d_in[3];
  const float* ada_w  = (const float*)d_in[4];
  const float* ada_b  = (const float*)d_in[5];
  const float* qkv_w  = (const float*)d_in[6];
  const float* qkv_b  = (const float*)d_in[7];
  const float* proj_w = (const float*)d_in[8];
  const float* proj_b = (const float*)d_in[9];

  char* ws = (char*)d_ws;
  float* scsh     = (float*)(ws);                  //   4 KB  [2][512]
  short* qkv_wt   = (short*)(ws + 4096);           // 384 KB  [768][256]
  short* proj_wt  = (short*)(ws + 397312);         // 128 KB  [256][256]
  short* xb       = (short*)(ws + 528384);         //   4 MB  [8192][256]
  short* qk_out   = (short*)(ws + 4722688);        //   8 MB  [8192][512]
  short* vT       = (short*)(ws + 13111296);       //   4 MB  [16][32][4096]
  short* attn_out = (short*)(ws + 17305600);       //   4 MB  [8192][256]
  short* OpB      = (short*)(ws + 21499904);       //  16 MB  [4][16][4096][32] bf16
  float* lpart    = (float*)(ws + 38277120);       //   1 MB  [4][16][4096]

  // scale * log2(e): softmax done in exp2 domain, folded into Q columns
  const float QS = 0.17677669529663687f * 1.4426950408889634f;

  prep_kernel<<<80, 256, 0, stream>>>(emb, t, ada_w, ada_b, scsh,
                                      qkv_w, qkv_wt, proj_w, proj_wt);
  ln_kernel<<<2048, 256, 0, stream>>>(x, scsh, xb);
  gemm_bf16<<<dim3(64, 12), 256, 0, stream>>>(xb, qkv_wt, qkv_b, 768, 0, QS,
                                              qk_out, vT, nullptr);
  attn_kernel<<<1024, 256, 0, stream>>>(qk_out, vT, OpB, lpart);
  reduce_kernel<<<8192, 256, 0, stream>>>(OpB, lpart, attn_out);
  gemm_bf16<<<dim3(64, 4), 256, 0, stream>>>(attn_out, proj_wt, proj_b, 256, 1,
                                             1.0f, nullptr, nullptr, (float*)d_out);
}